// Round 6
// baseline (504.661 us; speedup 1.0000x reference)
//
#include <hip/hip_runtime.h>

#define NBINS (640 * 640)
#define NXCD  8

typedef float f4 __attribute__((ext_vector_type(4)));

// Hardware XCD id (0..7 on MI355X), wave-uniform. [learn_hip m09]
__device__ __forceinline__ unsigned xcd_id() {
    unsigned x;
    asm("s_getreg_b32 %0, hwreg(HW_REG_XCC_ID)" : "=s"(x));
    return x & (NXCD - 1);
}

// Exact reference arithmetic: IEEE f32 div/mul, trunc cast. Returns bin in
// [0, NBINS) or -1 (fails mask, or segment_max OOB-drop when x/70.4 rounds
// up to 1.0 at the boundary — reference drops idx >= NBINS identically).
__device__ __forceinline__ int point_bin(f4 p, float l00, float l01, float l10,
                                         float l11, float dx, float dy,
                                         float fs0, float fs1, int s0) {
    bool m = (p.x > l00) & (p.x < l01) & (p.y > l10) & (p.y < l11);
    if (!m) return -1;
    int xi = (int)((p.x - l00) / dx * fs0);
    int yi = (int)((p.y - l10) / dy * fs1);
    int t = xi * s0 + yi;            // mask => xi,yi >= 0; max fits i32
    return (t < NBINS) ? t : -1;
}

__device__ __forceinline__ void l2_atomic_max(float* addr, float v) {
    // Non-negative floats order as their int bit patterns. Workgroup scope
    // keeps the RMW in the XCD-local L2 (no fabric coherence round-trip);
    // all writers of this copy are on this XCD, so that is sufficient.
    (void)__hip_atomic_fetch_max((int*)addr, __float_as_int(v),
                                 __ATOMIC_RELAXED, __HIP_MEMORY_SCOPE_WORKGROUP);
}

// ---------------- Pass 1: stream + per-XCD L2-local scatter ----------------
__global__ __launch_bounds__(256) void pfe_scatter_xcd(
    const f4* __restrict__ pc, const float* __restrict__ lim,
    const int* __restrict__ size, f4* __restrict__ pc_masked,
    float* __restrict__ copies, int n) {
    const float l00 = lim[0], l01 = lim[1], l10 = lim[2], l11 = lim[3];
    const int s0 = size[0];
    const float fs0 = (float)size[0], fs1 = (float)size[1];
    const float dx = l01 - l00, dy = l11 - l10;
    const f4 zero = {0.f, 0.f, 0.f, 0.f};

    float* myseg = copies + (size_t)xcd_id() * NBINS * 4;

    const int stride = gridDim.x * blockDim.x;
    int base = blockIdx.x * blockDim.x + threadIdx.x;
    for (; base < n; base += 4 * stride) {
        f4 p[4]; bool live[4]; int bin[4];
        #pragma unroll
        for (int u = 0; u < 4; ++u) {
            const int i = base + u * stride;
            live[u] = i < n;
            p[u] = live[u] ? pc[i] : (f4){l00, l10, 0.f, 0.f};  // fails mask
        }
        #pragma unroll
        for (int u = 0; u < 4; ++u) {
            bin[u] = point_bin(p[u], l00, l01, l10, l11, dx, dy, fs0, fs1, s0);
            if (live[u])
                __builtin_nontemporal_store(bin[u] >= 0 ? p[u] : zero,
                                            &pc_masked[base + u * stride]);
        }
        // Snapshot filter: copy values only grow from 0, so a plain (L1/L2)
        // read sees <= truth; skipping p <= cur is safe, cur >= 0 subsumes
        // the positivity requirement.
        f4 cur[4];
        #pragma unroll
        for (int u = 0; u < 4; ++u)
            if (bin[u] >= 0) cur[u] = *(const f4*)(myseg + (size_t)bin[u] * 4);
        #pragma unroll
        for (int u = 0; u < 4; ++u) {
            if (bin[u] < 0) continue;
            float* b = myseg + (size_t)bin[u] * 4;
            if (p[u].x > cur[u].x) l2_atomic_max(&b[0], p[u].x);
            if (p[u].y > cur[u].y) l2_atomic_max(&b[1], p[u].y);
            if (p[u].z > cur[u].z) l2_atomic_max(&b[2], p[u].z);
            if (p[u].w > cur[u].w) l2_atomic_max(&b[3], p[u].w);
        }
    }
}

// ---------------- Pass 2: reduce 8 copies -> seg ----------------
__global__ __launch_bounds__(256) void pfe_reduce_xcd(
    const float* __restrict__ copies, float* __restrict__ seg) {
    int b = blockIdx.x * blockDim.x + threadIdx.x;   // one bin (4 channels)
    if (b >= NBINS) return;
    f4 m = {0.f, 0.f, 0.f, 0.f};                     // zero-init => max(.,0)
    #pragma unroll
    for (int k = 0; k < NXCD; ++k) {
        f4 v = *(const f4*)(copies + ((size_t)k * NBINS + b) * 4);
        m.x = fmaxf(m.x, v.x);
        m.y = fmaxf(m.y, v.y);
        m.z = fmaxf(m.z, v.z);
        m.w = fmaxf(m.w, v.w);
    }
    *(f4*)(seg + (size_t)b * 4) = m;
}

// ---------------- Fallback (round-4 kernel, proven) ----------------
__global__ __launch_bounds__(256) void pfe_scatter_kernel(
    const f4* __restrict__ pc, const float* __restrict__ lim,
    const int* __restrict__ size, f4* __restrict__ pc_masked,
    float* __restrict__ seg, int n) {
    const float l00 = lim[0], l01 = lim[1], l10 = lim[2], l11 = lim[3];
    const int s0 = size[0];
    const float fs0 = (float)size[0], fs1 = (float)size[1];
    const float dx = l01 - l00, dy = l11 - l10;
    const f4 zero = {0.f, 0.f, 0.f, 0.f};

    const int stride = gridDim.x * blockDim.x;
    int base = blockIdx.x * blockDim.x + threadIdx.x;
    for (; base < n; base += 4 * stride) {
        f4 p[4]; bool live[4]; int bin[4];
        #pragma unroll
        for (int u = 0; u < 4; ++u) {
            const int i = base + u * stride;
            live[u] = i < n;
            p[u] = live[u] ? pc[i] : (f4){l00, l10, 0.f, 0.f};
        }
        #pragma unroll
        for (int u = 0; u < 4; ++u) {
            bin[u] = point_bin(p[u], l00, l01, l10, l11, dx, dy, fs0, fs1, s0);
            if (live[u])
                __builtin_nontemporal_store(bin[u] >= 0 ? p[u] : zero,
                                            &pc_masked[base + u * stride]);
        }
        f4 cur[4];
        #pragma unroll
        for (int u = 0; u < 4; ++u)
            if (bin[u] >= 0) cur[u] = *(const f4*)(seg + (size_t)bin[u] * 4);
        #pragma unroll
        for (int u = 0; u < 4; ++u) {
            if (bin[u] < 0) continue;
            float* b = seg + (size_t)bin[u] * 4;
            if (p[u].x > cur[u].x) atomicMax((int*)&b[0], __float_as_int(p[u].x));
            if (p[u].y > cur[u].y) atomicMax((int*)&b[1], __float_as_int(p[u].y));
            if (p[u].z > cur[u].z) atomicMax((int*)&b[2], __float_as_int(p[u].z));
            if (p[u].w > cur[u].w) atomicMax((int*)&b[3], __float_as_int(p[u].w));
        }
    }
}

extern "C" void kernel_launch(void* const* d_in, const int* in_sizes, int n_in,
                              void* d_out, int out_size, void* d_ws, size_t ws_size,
                              hipStream_t stream) {
    const f4*    pc  = (const f4*)d_in[0];
    const float* lim = (const float*)d_in[1];
    const int*   sz  = (const int*)d_in[2];

    const int n = in_sizes[0] / 4;             // 8,000,000 points
    float* out       = (float*)d_out;
    float* pc_masked = out;                    // n*4 floats
    float* seg       = out + (size_t)n * 4;    // NBINS*4 floats

    const size_t copies_bytes = (size_t)NXCD * NBINS * 4 * sizeof(float); // 52.4MB

    if (ws_size >= copies_bytes) {
        float* copies = (float*)d_ws;
        (void)hipMemsetAsync(copies, 0, copies_bytes, stream);

        pfe_scatter_xcd<<<2048, 256, 0, stream>>>(
            pc, lim, sz, (f4*)pc_masked, copies, n);
        pfe_reduce_xcd<<<(NBINS + 255) / 256, 256, 0, stream>>>(copies, seg);
    } else {
        (void)hipMemsetAsync(seg, 0, (size_t)NBINS * 4 * sizeof(float), stream);
        pfe_scatter_kernel<<<2048, 256, 0, stream>>>(
            pc, lim, sz, (f4*)pc_masked, seg, n);
    }
}

// Round 7
// 147.451 us; speedup vs baseline: 3.4226x; 3.4226x over previous
//
#include <hip/hip_runtime.h>

#define NBINS        (640 * 640)
#define GRID_X       640
#define REGIONS      128
#define BINS_PER_REG (GRID_X * 5)        // 5 rows per region = 3200 bins
#define P1_BLOCK     256
#define P1_PTS       4096                // points per pass-1 block
#define P1_K         (P1_PTS / P1_BLOCK) // 16
#define SCAP         3072                // LDS staging slots (mean 2714, sd 30)
#define P2_BLOCK     1024
#define CAP_MAX      49152               // bucket slots/region (mean 41.4k)
#define CAP_MIN      45056

typedef float f4 __attribute__((ext_vector_type(4)));

// Exact reference arithmetic: IEEE f32 div/mul, trunc cast. Returns bin in
// [0, NBINS) or -1 (fails mask, or segment_max OOB-drop at the x-boundary).
// Note yi may round to 640 (y -> 40-): bin aliases into row xi+1 exactly as
// the reference's idx = xi*640+yi does — we reproduce it bit-for-bit.
__device__ __forceinline__ int point_bin(f4 p, float l00, float l01, float l10,
                                         float l11, float dx, float dy,
                                         float fs0, float fs1, int s0) {
    bool m = (p.x > l00) & (p.x < l01) & (p.y > l10) & (p.y < l11);
    if (!m) return -1;
    int xi = (int)((p.x - l00) / dx * fs0);
    int yi = (int)((p.y - l10) / dy * fs1);
    int t = xi * s0 + yi;            // mask => xi,yi >= 0; max fits i32
    return (t < NBINS) ? t : -1;
}

__device__ __forceinline__ void dev_atomic_max_filtered(float* b, f4 p, f4 cur) {
    if (p.x > cur.x) atomicMax((int*)&b[0], __float_as_int(p.x));
    if (p.y > cur.y) atomicMax((int*)&b[1], __float_as_int(p.y));
    if (p.z > cur.z) atomicMax((int*)&b[2], __float_as_int(p.z));
    if (p.w > cur.w) atomicMax((int*)&b[3], __float_as_int(p.w));
}

// ---------------- Pass 1: stream + LDS-staged coalesced bucketing ----------
__global__ __launch_bounds__(P1_BLOCK) void pfe_pass1(
    const f4* __restrict__ pc, const float* __restrict__ lim,
    const int* __restrict__ size, f4* __restrict__ pc_masked,
    float* __restrict__ seg, f4* __restrict__ bvals,
    unsigned* __restrict__ bbins, unsigned* __restrict__ cursors,
    int cap, int n) {
    __shared__ f4       sval[SCAP];
    __shared__ unsigned sbin[SCAP];
    __shared__ unsigned hist[REGIONS], lstart[REGIONS], woff[REGIONS];
    __shared__ unsigned gbase[REGIONS], scan[REGIONS];
    __shared__ unsigned stotal;

    const float l00 = lim[0], l01 = lim[1], l10 = lim[2], l11 = lim[3];
    const int s0 = size[0];
    const float fs0 = (float)size[0], fs1 = (float)size[1];
    const float dx = l01 - l00, dy = l11 - l10;
    const f4 zero = {0.f, 0.f, 0.f, 0.f};
    const int tid = threadIdx.x;

    if (tid < REGIONS) hist[tid] = 0;
    __syncthreads();

    const int base = blockIdx.x * P1_PTS;

    // Phase A: stream pc_masked (nt, write-once), count per-region points.
    for (int k = 0; k < P1_K; ++k) {
        int i = base + k * P1_BLOCK + tid;
        if (i < n) {
            f4 p = pc[i];
            int bin = point_bin(p, l00, l01, l10, l11, dx, dy, fs0, fs1, s0);
            __builtin_nontemporal_store(bin >= 0 ? p : zero, &pc_masked[i]);
            if (bin >= 0) atomicAdd(&hist[(unsigned)bin / BINS_PER_REG], 1u);
        }
    }
    __syncthreads();

    // Reserve global bucket space (long-latency device atomic, issued early
    // so it overlaps the scan + Phase C below).
    if (tid < REGIONS) {
        unsigned c = hist[tid];
        gbase[tid] = c ? atomicAdd(&cursors[tid], c) : 0u;
        scan[tid]  = c;
        woff[tid]  = 0;
    }
    __syncthreads();

    // Exclusive prefix over hist (Hillis-Steele, 7 steps).
    for (int off = 1; off < REGIONS; off <<= 1) {
        unsigned t = 0;
        if (tid < REGIONS && tid >= off) t = scan[tid - off];
        __syncthreads();
        if (tid < REGIONS) scan[tid] += t;
        __syncthreads();
    }
    if (tid < REGIONS) lstart[tid] = scan[tid] - hist[tid];
    if (tid == REGIONS - 1) stotal = scan[REGIONS - 1];
    __syncthreads();

    // Phase C: re-read chunk (L1/L2-hot), stage grouped-by-region into LDS.
    for (int k = 0; k < P1_K; ++k) {
        int i = base + k * P1_BLOCK + tid;
        if (i < n) {
            f4 p = pc[i];
            int bin = point_bin(p, l00, l01, l10, l11, dx, dy, fs0, fs1, s0);
            if (bin >= 0) {
                unsigned r = (unsigned)bin / BINS_PER_REG;
                unsigned s = atomicAdd(&woff[r], 1u);     // local slot
                unsigned idx = lstart[r] + s;
                if (idx < SCAP) {
                    sval[idx] = p;
                    sbin[idx] = (unsigned)bin;
                } else {
                    // Staging overflow (statistically never): write the
                    // reserved slot directly so pass 2 never reads garbage.
                    unsigned goff = gbase[r] + s;
                    if (goff < (unsigned)cap) {
                        size_t slot = (size_t)r * cap + goff;
                        bvals[slot] = p;
                        bbins[slot] = (unsigned)bin;
                    } else {
                        float* b = seg + (size_t)bin * 4;
                        dev_atomic_max_filtered(b, p, *(const f4*)b);
                    }
                }
            }
        }
    }
    __syncthreads();

    // Flush: dense sweep over staged points -> contiguous per-region runs.
    const unsigned m = stotal < SCAP ? stotal : SCAP;
    for (unsigned j = tid; j < m; j += P1_BLOCK) {
        unsigned bin = sbin[j];
        unsigned r = bin / BINS_PER_REG;
        unsigned goff = gbase[r] + (j - lstart[r]);
        if (goff < (unsigned)cap) {
            size_t slot = (size_t)r * cap + goff;
            bvals[slot] = sval[j];
            bbins[slot] = bin;
        } else {
            // Bucket overflow: filtered device atomics (merged by pass 2).
            f4 p = sval[j];
            float* b = seg + (size_t)bin * 4;
            dev_atomic_max_filtered(b, p, *(const f4*)b);
        }
    }
}

// ---------------- Pass 2: exclusive gather per region ----------------
__global__ __launch_bounds__(P2_BLOCK) void pfe_pass2(
    const f4* __restrict__ bvals, const unsigned* __restrict__ bbins,
    const unsigned* __restrict__ cursors, int cap, float* __restrict__ seg) {
    const int r = blockIdx.x;
    const int b0 = r * BINS_PER_REG;

    __shared__ int tile[BINS_PER_REG * 4];           // fp32 bits, all >= 0
    for (int j = threadIdx.x; j < BINS_PER_REG * 4; j += P2_BLOCK) tile[j] = 0;
    __syncthreads();

    unsigned cf = cursors[r];
    int cnt = (int)(cf < (unsigned)cap ? cf : (unsigned)cap);
    const size_t rb = (size_t)r * cap;
    for (int i = threadIdx.x; i < cnt; i += P2_BLOCK) {
        unsigned bin = bbins[rb + i];
        f4 v = bvals[rb + i];
        int t = ((int)bin - b0) * 4;
        // Non-negative floats order as their int bits; skip non-positives.
        if (v.x > 0.f) atomicMax(&tile[t + 0], __float_as_int(v.x));
        if (v.y > 0.f) atomicMax(&tile[t + 1], __float_as_int(v.y));
        if (v.z > 0.f) atomicMax(&tile[t + 2], __float_as_int(v.z));
        if (v.w > 0.f) atomicMax(&tile[t + 3], __float_as_int(v.w));
    }
    __syncthreads();

    // Merge with seg (holds only rare overflow-path maxes, else zeros).
    for (int j = threadIdx.x; j < BINS_PER_REG; j += P2_BLOCK) {
        f4 s = *(const f4*)(seg + (size_t)(b0 + j) * 4);
        f4 o;
        o.x = fmaxf(__int_as_float(tile[j * 4 + 0]), s.x);
        o.y = fmaxf(__int_as_float(tile[j * 4 + 1]), s.y);
        o.z = fmaxf(__int_as_float(tile[j * 4 + 2]), s.z);
        o.w = fmaxf(__int_as_float(tile[j * 4 + 3]), s.w);
        *(f4*)(seg + (size_t)(b0 + j) * 4) = o;
    }
}

// ---------------- Fallback (round-4 kernel, proven) ----------------
__global__ __launch_bounds__(256) void pfe_scatter_kernel(
    const f4* __restrict__ pc, const float* __restrict__ lim,
    const int* __restrict__ size, f4* __restrict__ pc_masked,
    float* __restrict__ seg, int n) {
    const float l00 = lim[0], l01 = lim[1], l10 = lim[2], l11 = lim[3];
    const int s0 = size[0];
    const float fs0 = (float)size[0], fs1 = (float)size[1];
    const float dx = l01 - l00, dy = l11 - l10;
    const f4 zero = {0.f, 0.f, 0.f, 0.f};

    const int stride = gridDim.x * blockDim.x;
    int base = blockIdx.x * blockDim.x + threadIdx.x;
    for (; base < n; base += 4 * stride) {
        f4 p[4]; bool live[4]; int bin[4];
        #pragma unroll
        for (int u = 0; u < 4; ++u) {
            const int i = base + u * stride;
            live[u] = i < n;
            p[u] = live[u] ? pc[i] : (f4){l00, l10, 0.f, 0.f};
        }
        #pragma unroll
        for (int u = 0; u < 4; ++u) {
            bin[u] = point_bin(p[u], l00, l01, l10, l11, dx, dy, fs0, fs1, s0);
            if (live[u])
                __builtin_nontemporal_store(bin[u] >= 0 ? p[u] : zero,
                                            &pc_masked[base + u * stride]);
        }
        f4 cur[4];
        #pragma unroll
        for (int u = 0; u < 4; ++u)
            if (bin[u] >= 0) cur[u] = *(const f4*)(seg + (size_t)bin[u] * 4);
        #pragma unroll
        for (int u = 0; u < 4; ++u) {
            if (bin[u] < 0) continue;
            dev_atomic_max_filtered(seg + (size_t)bin[u] * 4, p[u], cur[u]);
        }
    }
}

extern "C" void kernel_launch(void* const* d_in, const int* in_sizes, int n_in,
                              void* d_out, int out_size, void* d_ws, size_t ws_size,
                              hipStream_t stream) {
    const f4*    pc  = (const f4*)d_in[0];
    const float* lim = (const float*)d_in[1];
    const int*   sz  = (const int*)d_in[2];

    const int n = in_sizes[0] / 4;             // 8,000,000 points
    float* out       = (float*)d_out;
    float* pc_masked = out;                    // n*4 floats
    float* seg       = out + (size_t)n * 4;    // NBINS*4 floats

    (void)hipMemsetAsync(seg, 0, (size_t)NBINS * 4 * sizeof(float), stream);

    // Workspace: bvals f4[REGIONS*cap] | bbins u32[REGIONS*cap] | cursors[128]
    long long cap = 0;
    const size_t fixed = REGIONS * sizeof(unsigned);
    if (ws_size > fixed)
        cap = (long long)((ws_size - fixed) / ((size_t)REGIONS * 20));
    if (cap > CAP_MAX) cap = CAP_MAX;

    if (cap >= CAP_MIN) {
        f4*       bvals   = (f4*)d_ws;
        unsigned* bbins   = (unsigned*)(bvals + (size_t)REGIONS * cap);
        unsigned* cursors = bbins + (size_t)REGIONS * cap;

        (void)hipMemsetAsync(cursors, 0, REGIONS * sizeof(unsigned), stream);

        const int p1_grid = (n + P1_PTS - 1) / P1_PTS;   // 1954
        pfe_pass1<<<p1_grid, P1_BLOCK, 0, stream>>>(
            pc, lim, sz, (f4*)pc_masked, seg, bvals, bbins, cursors,
            (int)cap, n);
        pfe_pass2<<<REGIONS, P2_BLOCK, 0, stream>>>(
            bvals, bbins, cursors, (int)cap, seg);
    } else {
        pfe_scatter_kernel<<<2048, 256, 0, stream>>>(
            pc, lim, sz, (f4*)pc_masked, seg, n);
    }
}

// Round 8
// 127.510 us; speedup vs baseline: 3.9578x; 1.1564x over previous
//
#include <hip/hip_runtime.h>

#define NBINS        (640 * 640)
#define GRID_X       640
#define REGIONS      128
#define BINS_PER_REG (GRID_X * 5)        // 5 rows per region = 3200 bins
#define P1_BLOCK     512
#define P1_PTS       2048                // points per pass-1 block
#define P1_K         (P1_PTS / P1_BLOCK) // 4, register-held
#define SCAP         1600                // LDS staging slots (mean 1357, sd 21)
#define P2_BLOCK     1024
#define CAP_MAX      49152               // bucket slots/region (mean 41.4k)
#define CAP_MIN      45056

typedef float f4 __attribute__((ext_vector_type(4)));

// Exact reference arithmetic: IEEE f32 div/mul, trunc cast. Returns bin in
// [0, NBINS) or -1 (fails mask, or segment_max OOB-drop at the x-boundary).
__device__ __forceinline__ int point_bin(f4 p, float l00, float l01, float l10,
                                         float l11, float dx, float dy,
                                         float fs0, float fs1, int s0) {
    bool m = (p.x > l00) & (p.x < l01) & (p.y > l10) & (p.y < l11);
    if (!m) return -1;
    int xi = (int)((p.x - l00) / dx * fs0);
    int yi = (int)((p.y - l10) / dy * fs1);
    int t = xi * s0 + yi;            // mask => xi,yi >= 0; max fits i32
    return (t < NBINS) ? t : -1;
}

__device__ __forceinline__ void dev_atomic_max_filtered(float* b, f4 p, f4 cur) {
    if (p.x > cur.x) atomicMax((int*)&b[0], __float_as_int(p.x));
    if (p.y > cur.y) atomicMax((int*)&b[1], __float_as_int(p.y));
    if (p.z > cur.z) atomicMax((int*)&b[2], __float_as_int(p.z));
    if (p.w > cur.w) atomicMax((int*)&b[3], __float_as_int(p.w));
}

// ------- Pass 1: stream + register-held points + LDS-grouped bucketing -----
__global__ __launch_bounds__(P1_BLOCK) void pfe_pass1(
    const f4* __restrict__ pc, const float* __restrict__ lim,
    const int* __restrict__ size, f4* __restrict__ pc_masked,
    float* __restrict__ seg, f4* __restrict__ bvals,
    unsigned* __restrict__ bbins, unsigned* __restrict__ cursors,
    int cap, int n) {
    __shared__ f4       sval[SCAP];
    __shared__ unsigned sbin[SCAP];
    __shared__ unsigned hist[REGIONS], lstart[REGIONS], woff[REGIONS];
    __shared__ unsigned gbase[REGIONS], scan[REGIONS];
    __shared__ unsigned stotal;

    const float l00 = lim[0], l01 = lim[1], l10 = lim[2], l11 = lim[3];
    const int s0 = size[0];
    const float fs0 = (float)size[0], fs1 = (float)size[1];
    const float dx = l01 - l00, dy = l11 - l10;
    const f4 zero = {0.f, 0.f, 0.f, 0.f};
    const int tid = threadIdx.x;

    if (tid < REGIONS) hist[tid] = 0;
    __syncthreads();

    const int base = blockIdx.x * P1_PTS;

    // Phase A: issue all K loads, then mask/bin/stream + LDS histogram.
    // Points stay in registers across the barriers (no global re-read).
    f4  p[P1_K];
    int bin[P1_K];
    #pragma unroll
    for (int k = 0; k < P1_K; ++k) {
        int i = base + k * P1_BLOCK + tid;
        p[k] = (i < n) ? pc[i] : (f4){l00, l10, 0.f, 0.f};  // fails mask
    }
    #pragma unroll
    for (int k = 0; k < P1_K; ++k) {
        int i = base + k * P1_BLOCK + tid;
        bin[k] = point_bin(p[k], l00, l01, l10, l11, dx, dy, fs0, fs1, s0);
        if (i < n)
            __builtin_nontemporal_store(bin[k] >= 0 ? p[k] : zero,
                                        &pc_masked[i]);
        if (bin[k] >= 0)
            atomicAdd(&hist[(unsigned)bin[k] / BINS_PER_REG], 1u);
    }
    __syncthreads();

    // Reserve global bucket space (long-latency device atomic, issued early
    // so it overlaps the scan below).
    if (tid < REGIONS) {
        unsigned c = hist[tid];
        gbase[tid] = c ? atomicAdd(&cursors[tid], c) : 0u;
        scan[tid]  = c;
        woff[tid]  = 0;
    }
    __syncthreads();

    // Exclusive prefix over hist (Hillis-Steele, 7 steps; tid<128 active).
    for (int off = 1; off < REGIONS; off <<= 1) {
        unsigned t = 0;
        if (tid < REGIONS && tid >= off) t = scan[tid - off];
        __syncthreads();
        if (tid < REGIONS) scan[tid] += t;
        __syncthreads();
    }
    if (tid < REGIONS) lstart[tid] = scan[tid] - hist[tid];
    if (tid == REGIONS - 1) stotal = scan[REGIONS - 1];
    __syncthreads();

    // Phase C: scatter register-held points into grouped LDS staging.
    #pragma unroll
    for (int k = 0; k < P1_K; ++k) {
        if (bin[k] >= 0) {
            unsigned r = (unsigned)bin[k] / BINS_PER_REG;
            unsigned s = atomicAdd(&woff[r], 1u);     // local slot
            unsigned idx = lstart[r] + s;
            if (idx < SCAP) {
                sval[idx] = p[k];
                sbin[idx] = (unsigned)bin[k];
            } else {
                // Staging overflow (statistically never): write the reserved
                // slot directly so pass 2 never reads garbage.
                unsigned goff = gbase[r] + s;
                if (goff < (unsigned)cap) {
                    size_t slot = (size_t)r * cap + goff;
                    bvals[slot] = p[k];
                    bbins[slot] = (unsigned)bin[k];
                } else {
                    float* b = seg + (size_t)bin[k] * 4;
                    dev_atomic_max_filtered(b, p[k], *(const f4*)b);
                }
            }
        }
    }
    __syncthreads();

    // Flush: dense sweep over staged points -> contiguous per-region runs.
    const unsigned m = stotal < SCAP ? stotal : SCAP;
    for (unsigned j = tid; j < m; j += P1_BLOCK) {
        unsigned bn = sbin[j];
        unsigned r = bn / BINS_PER_REG;
        unsigned goff = gbase[r] + (j - lstart[r]);
        if (goff < (unsigned)cap) {
            size_t slot = (size_t)r * cap + goff;
            bvals[slot] = sval[j];
            bbins[slot] = bn;
        } else {
            // Bucket overflow: filtered device atomics (merged by pass 2).
            f4 v = sval[j];
            float* b = seg + (size_t)bn * 4;
            dev_atomic_max_filtered(b, v, *(const f4*)b);
        }
    }
}

// ---------------- Pass 2: exclusive gather per region ----------------
__global__ __launch_bounds__(P2_BLOCK) void pfe_pass2(
    const f4* __restrict__ bvals, const unsigned* __restrict__ bbins,
    const unsigned* __restrict__ cursors, int cap, float* __restrict__ seg) {
    const int r = blockIdx.x;
    const int b0 = r * BINS_PER_REG;

    __shared__ int tile[BINS_PER_REG * 4];           // fp32 bits, all >= 0
    for (int j = threadIdx.x; j < BINS_PER_REG * 4; j += P2_BLOCK) tile[j] = 0;
    __syncthreads();

    unsigned cf = cursors[r];
    int cnt = (int)(cf < (unsigned)cap ? cf : (unsigned)cap);
    const size_t rb = (size_t)r * cap;
    for (int i = threadIdx.x; i < cnt; i += P2_BLOCK) {
        unsigned bin = bbins[rb + i];
        f4 v = bvals[rb + i];
        int t = ((int)bin - b0) * 4;
        // Non-negative floats order as their int bits; skip non-positives.
        if (v.x > 0.f) atomicMax(&tile[t + 0], __float_as_int(v.x));
        if (v.y > 0.f) atomicMax(&tile[t + 1], __float_as_int(v.y));
        if (v.z > 0.f) atomicMax(&tile[t + 2], __float_as_int(v.z));
        if (v.w > 0.f) atomicMax(&tile[t + 3], __float_as_int(v.w));
    }
    __syncthreads();

    // Merge with seg (holds only rare overflow-path maxes, else zeros).
    for (int j = threadIdx.x; j < BINS_PER_REG; j += P2_BLOCK) {
        f4 s = *(const f4*)(seg + (size_t)(b0 + j) * 4);
        f4 o;
        o.x = fmaxf(__int_as_float(tile[j * 4 + 0]), s.x);
        o.y = fmaxf(__int_as_float(tile[j * 4 + 1]), s.y);
        o.z = fmaxf(__int_as_float(tile[j * 4 + 2]), s.z);
        o.w = fmaxf(__int_as_float(tile[j * 4 + 3]), s.w);
        *(f4*)(seg + (size_t)(b0 + j) * 4) = o;
    }
}

// ---------------- Fallback (round-4 kernel, proven) ----------------
__global__ __launch_bounds__(256) void pfe_scatter_kernel(
    const f4* __restrict__ pc, const float* __restrict__ lim,
    const int* __restrict__ size, f4* __restrict__ pc_masked,
    float* __restrict__ seg, int n) {
    const float l00 = lim[0], l01 = lim[1], l10 = lim[2], l11 = lim[3];
    const int s0 = size[0];
    const float fs0 = (float)size[0], fs1 = (float)size[1];
    const float dx = l01 - l00, dy = l11 - l10;
    const f4 zero = {0.f, 0.f, 0.f, 0.f};

    const int stride = gridDim.x * blockDim.x;
    int base = blockIdx.x * blockDim.x + threadIdx.x;
    for (; base < n; base += 4 * stride) {
        f4 p[4]; bool live[4]; int bin[4];
        #pragma unroll
        for (int u = 0; u < 4; ++u) {
            const int i = base + u * stride;
            live[u] = i < n;
            p[u] = live[u] ? pc[i] : (f4){l00, l10, 0.f, 0.f};
        }
        #pragma unroll
        for (int u = 0; u < 4; ++u) {
            bin[u] = point_bin(p[u], l00, l01, l10, l11, dx, dy, fs0, fs1, s0);
            if (live[u])
                __builtin_nontemporal_store(bin[u] >= 0 ? p[u] : zero,
                                            &pc_masked[base + u * stride]);
        }
        f4 cur[4];
        #pragma unroll
        for (int u = 0; u < 4; ++u)
            if (bin[u] >= 0) cur[u] = *(const f4*)(seg + (size_t)bin[u] * 4);
        #pragma unroll
        for (int u = 0; u < 4; ++u) {
            if (bin[u] < 0) continue;
            dev_atomic_max_filtered(seg + (size_t)bin[u] * 4, p[u], cur[u]);
        }
    }
}

extern "C" void kernel_launch(void* const* d_in, const int* in_sizes, int n_in,
                              void* d_out, int out_size, void* d_ws, size_t ws_size,
                              hipStream_t stream) {
    const f4*    pc  = (const f4*)d_in[0];
    const float* lim = (const float*)d_in[1];
    const int*   sz  = (const int*)d_in[2];

    const int n = in_sizes[0] / 4;             // 8,000,000 points
    float* out       = (float*)d_out;
    float* pc_masked = out;                    // n*4 floats
    float* seg       = out + (size_t)n * 4;    // NBINS*4 floats

    (void)hipMemsetAsync(seg, 0, (size_t)NBINS * 4 * sizeof(float), stream);

    // Workspace: bvals f4[REGIONS*cap] | bbins u32[REGIONS*cap] | cursors[128]
    long long cap = 0;
    const size_t fixed = REGIONS * sizeof(unsigned);
    if (ws_size > fixed)
        cap = (long long)((ws_size - fixed) / ((size_t)REGIONS * 20));
    if (cap > CAP_MAX) cap = CAP_MAX;

    if (cap >= CAP_MIN) {
        f4*       bvals   = (f4*)d_ws;
        unsigned* bbins   = (unsigned*)(bvals + (size_t)REGIONS * cap);
        unsigned* cursors = bbins + (size_t)REGIONS * cap;

        (void)hipMemsetAsync(cursors, 0, REGIONS * sizeof(unsigned), stream);

        const int p1_grid = (n + P1_PTS - 1) / P1_PTS;   // 3907
        pfe_pass1<<<p1_grid, P1_BLOCK, 0, stream>>>(
            pc, lim, sz, (f4*)pc_masked, seg, bvals, bbins, cursors,
            (int)cap, n);
        pfe_pass2<<<REGIONS, P2_BLOCK, 0, stream>>>(
            bvals, bbins, cursors, (int)cap, seg);
    } else {
        pfe_scatter_kernel<<<2048, 256, 0, stream>>>(
            pc, lim, sz, (f4*)pc_masked, seg, n);
    }
}